// Round 8
// baseline (207.185 us; speedup 1.0000x reference)
//
#include <hip/hip_runtime.h>
#include <math.h>

#define BSZ 2
#define TSEQ 2048
#define CDIM 1024
#define HNUM 16

typedef __attribute__((ext_vector_type(8))) short bhalf8;
typedef __attribute__((ext_vector_type(4))) short bhalf4;
typedef __attribute__((ext_vector_type(4))) float floatx4;

__device__ __forceinline__ unsigned short f2bf(float f) {
    union { float f; unsigned u; } v;
    v.f = f;
    unsigned r = v.u + 0x7FFFu + ((v.u >> 16) & 1u);
    return (unsigned short)(r >> 16);
}

__device__ __forceinline__ floatx4 fx4_zero() { floatx4 z = {0.f,0.f,0.f,0.f}; return z; }

// async global->LDS, 16 B per lane. lds dest = (wave-uniform base) + lane*16.
typedef __attribute__((address_space(3))) unsigned int lds_u32;
typedef const __attribute__((address_space(1))) unsigned int g_u32;
__device__ __forceinline__ void async_copy16(const void* g, void* l) {
    __builtin_amdgcn_global_load_lds((g_u32*)g, (lds_u32*)l, 16, 0, 0);
}

// ---------------------------------------------------------------------------
// Merged prepass (one launch):
//  blocks [0,2048):    x fp32 -> xb bf16 (8 elems/thread)
//  blocks [2048,5120): W_attn [1024,3072] -> WtA [3072,1024] bf16 transpose
//  blocks [5120,6144): W_proj [1024,1024] -> WtP [1024,1024] bf16 transpose
// (no XCD remap: streaming, no inter-block reuse -- T1 null regime)
// ---------------------------------------------------------------------------
__device__ __forceinline__ void trans_tile(
    const float* __restrict__ W, unsigned short* __restrict__ Wt,
    int K, int N, int n0, int k0, int tid, float (*t)[33])
{
    const int tx = tid & 31, ty = tid >> 5;
#pragma unroll
    for (int i = 0; i < 4; ++i)
        t[ty + i * 8][tx] = W[(size_t)(k0 + ty + i * 8) * N + n0 + tx];
    __syncthreads();
#pragma unroll
    for (int i = 0; i < 4; ++i)
        Wt[(size_t)(n0 + ty + i * 8) * K + k0 + tx] = f2bf(t[tx][ty + i * 8]);
}

__global__ __launch_bounds__(256) void prepass(
    const float* __restrict__ x, unsigned short* __restrict__ xb,
    const float* __restrict__ Wa, unsigned short* __restrict__ WtA,
    const float* __restrict__ Wp, unsigned short* __restrict__ WtP)
{
    __shared__ float t[32][33];
    const int bid = blockIdx.x;
    const int tid = threadIdx.x;
    if (bid < 2048) {
        size_t i = ((size_t)bid * 256 + tid) * 8;
        float4 a = *(const float4*)(x + i);
        float4 b = *(const float4*)(x + i + 4);
        uint4 o;
        o.x = (unsigned)f2bf(a.x) | ((unsigned)f2bf(a.y) << 16);
        o.y = (unsigned)f2bf(a.z) | ((unsigned)f2bf(a.w) << 16);
        o.z = (unsigned)f2bf(b.x) | ((unsigned)f2bf(b.y) << 16);
        o.w = (unsigned)f2bf(b.z) | ((unsigned)f2bf(b.w) << 16);
        *(uint4*)(xb + i) = o;
    } else if (bid < 5120) {
        int tl = bid - 2048;                       // 96 n-tiles x 32 k-tiles
        trans_tile(Wa, WtA, 1024, 3072, (tl % 96) * 32, (tl / 96) * 32, tid, t);
    } else {
        int tl = bid - 5120;                       // 32 x 32
        trans_tile(Wp, WtP, 1024, 1024, (tl % 32) * 32, (tl / 32) * 32, tid, t);
    }
}

// ---------------------------------------------------------------------------
// bf16 MFMA GEMM (B^T input) + bias, single-barrier double-buffered K-loop.
// C[M,N] = A[M,K] @ Bt[N,K]^T + bias[N].  Block tile BM x BN, BK=32,
// 256 threads (4 waves). Wave covers (BM/2)x(BN/2); acc = MTxNT of 16x16.
// T1 XCD remap: linear block id L runs on XCD L%8; logical tile
// swz = (L%8)*(nwg/8) + L/8 gives each XCD a contiguous bn-fastest chunk
// (A-panels + shared B stay L2-resident per XCD). nwg%8==0 for our grids.
// T2 LDS chunk swizzle: data (row r, k-chunk q) at slot (q+(r>>1))&3;
// staged via pre-swizzled GLOBAL source, read with sw8 (conflict-free).
// Blocks whose colbase >= v_start write TRANSPOSED to vt via ushort4.
// Columns < q_end get scaled by 0.125*log2(e) in fp32 before bf16 round.
// ---------------------------------------------------------------------------
template<int BM, int BN, bool OUT_BF16>
__global__ __launch_bounds__(256) void gemm_bt(
    const unsigned short* __restrict__ A, const unsigned short* __restrict__ Bt,
    const float* __restrict__ bias, void* __restrict__ Cp,
    int M, int N, int K, int v_start, unsigned short* __restrict__ vt, int q_end)
{
    constexpr int ALINES = BM / 64;
    constexpr int BLINES = BN / 64;
    constexpr int MT = BM / 32;
    constexpr int NT = BN / 32;
    __shared__ unsigned short As[2][BM * 32];
    __shared__ unsigned short Bs[2][BN * 32];

    const int tid   = threadIdx.x;
    // XCD-aware block remap (bijective: nwg % 8 == 0 for all launches)
    const int nx  = (int)gridDim.x;
    const int lin = (int)(blockIdx.y * gridDim.x + blockIdx.x);
    const int cpx = (int)(gridDim.x * gridDim.y) >> 3;
    const int swz = (lin & 7) * cpx + (lin >> 3);
    const int bn  = swz % nx;
    const int bm  = swz / nx;

    const int wave  = tid >> 6;
    const int col16 = tid & 15;
    const int quad  = (tid & 63) >> 4;
    const int wm    = (wave >> 1) * (BM / 2);
    const int wn    = (wave & 1) * (BN / 2);

    floatx4 acc[MT][NT];
#pragma unroll
    for (int i = 0; i < MT; ++i)
#pragma unroll
        for (int j = 0; j < NT; ++j) acc[i][j] = fx4_zero();

    // staging: lane covers row gr, global k-chunk pre-swizzled so that LDS
    // slot (gr, tid&3) holds chunk ((tid&3) - (gr>>1)) & 3
    const int gr = tid >> 2;
    const int gk = (((tid & 3) + 4 - ((tid >> 3) & 3)) & 3) * 8;
    const unsigned short* Ab = A  + (size_t)(bm * BM + gr) * K + gk;
    const unsigned short* Bb = Bt + (size_t)(bn * BN + gr) * K + gk;

    // fragment read: slot of k-chunk `quad` for row (.. + col16)
    const int sw8 = ((quad + (col16 >> 1)) & 3) * 8;

#define STAGE(k0, bf) { \
    char* AsB = (char*)As[bf] + wave * 1024; \
    char* BsB = (char*)Bs[bf] + wave * 1024; \
    _Pragma("unroll") \
    for (int l = 0; l < ALINES; ++l) \
        async_copy16(Ab + (size_t)l * 64 * K + (k0), AsB + l * 4096); \
    _Pragma("unroll") \
    for (int l = 0; l < BLINES; ++l) \
        async_copy16(Bb + (size_t)l * 64 * K + (k0), BsB + l * 4096); }

#define COMPUTE(bf) { \
    bhalf8 a[MT], b[NT]; \
    _Pragma("unroll") \
    for (int i = 0; i < MT; ++i) \
        a[i] = *(const bhalf8*)&As[bf][(wm + i * 16 + col16) * 32 + sw8]; \
    _Pragma("unroll") \
    for (int j = 0; j < NT; ++j) \
        b[j] = *(const bhalf8*)&Bs[bf][(wn + j * 16 + col16) * 32 + sw8]; \
    _Pragma("unroll") \
    for (int i = 0; i < MT; ++i) \
        _Pragma("unroll") \
        for (int j = 0; j < NT; ++j) \
            acc[i][j] = __builtin_amdgcn_mfma_f32_16x16x32_bf16(a[i], b[j], acc[i][j], 0, 0, 0); }

    STAGE(0, 0);
    __syncthreads();
    int buf = 0;
    for (int k0 = 0; k0 < K - 32; k0 += 32) {
        STAGE(k0 + 32, buf ^ 1);
        COMPUTE(buf);
        __syncthreads();
        buf ^= 1;
    }
    COMPUTE(buf);
#undef STAGE
#undef COMPUTE

    const int colbase = bn * BN + wn;
    const bool vpath = (v_start >= 0) && (colbase >= v_start);  // wave-uniform
    const float csc = (colbase < q_end) ? 0.18033688f : 1.0f;   // wave-uniform
#pragma unroll
    for (int j = 0; j < NT; ++j) {
        int col = colbase + j * 16 + col16;
        float bv = bias[col];
#pragma unroll
        for (int i = 0; i < MT; ++i) {
            if (vpath) {
                int row0 = bm * BM + wm + i * 16 + quad * 4;
                ushort4 o;
                o.x = f2bf((acc[i][j][0] + bv) * csc);
                o.y = f2bf((acc[i][j][1] + bv) * csc);
                o.z = f2bf((acc[i][j][2] + bv) * csc);
                o.w = f2bf((acc[i][j][3] + bv) * csc);
                size_t vrow = (size_t)((row0 >> 11) * 1024 + (col - v_start));
                *(ushort4*)(vt + vrow * 2048 + (row0 & 2047)) = o;
            } else {
#pragma unroll
                for (int r = 0; r < 4; ++r) {
                    int row = bm * BM + wm + i * 16 + quad * 4 + r;
                    float v = (acc[i][j][r] + bv) * csc;
                    if (OUT_BF16)
                        ((unsigned short*)Cp)[(size_t)row * N + col] = f2bf(v);
                    else
                        ((float*)Cp)[(size_t)row * N + col] = v;
                }
            }
        }
    }
}

// ---------------------------------------------------------------------------
// MFMA flash attention v6c: v6b (r2/r5-proven, 45.3 us, QBLK=64, 256 thr)
// + T1 XCD-aware block remap.  Grid 1024 = 8 x 128 exactly; XCD k owns the
// 128-block chunk = heads [4k,4k+4) x all 32 qb -> per-XCD K/V working set
// 4 x 512 KB = 2 MB, L2-resident (default round-robin churned 16 MB of KV
// through every 4 MB XCD L2).  Chunk is exactly co-resident (32 CU x 4
// blocks), identical work per chunk.  All math/layouts unchanged from v6b.
// NOTE: QBLK=128/512-thread restructure (r6/r7) REGRESSED (51-57 us,
// +2M unexplained bank conflicts) -- do not revisit without new evidence.
// K image:  row*128B + (chunk ^ (row&7))*16B   (async-staged; b128 reads
//   conflict-free). V image: Vt[d*76 + t], staged with global b128 +
//   ds_write; PV b64 read phase bank start = 6*col16 -> conflict-free.
// ---------------------------------------------------------------------------
template<bool DIAG>
__device__ __forceinline__ void attn_tile(
    const unsigned short* __restrict__ Ks, const unsigned short* __restrict__ Vt,
    const bhalf8* qf, floatx4* oT, floatx4& accl,
    int col16, int quad, int qloc)
{
    const int sx = col16 & 7;
    const floatx4 minusC = {-17.31234049f, -17.31234049f, -17.31234049f, -17.31234049f};
    const bhalf4 ones = {0x3F80, 0x3F80, 0x3F80, 0x3F80};   // bf16 1.0 x4

    floatx4 s[4];
#pragma unroll
    for (int n = 0; n < 4; ++n) {
        const int row = 16 * n + col16;
        bhalf8 k0 = *(const bhalf8*)&Ks[row * 64 + ((quad ^ sx) * 8)];
        bhalf8 k1 = *(const bhalf8*)&Ks[row * 64 + (((4 + quad) ^ sx) * 8)];
        floatx4 t = __builtin_amdgcn_mfma_f32_16x16x32_bf16(k0, qf[0], minusC, 0, 0, 0);
        s[n] = __builtin_amdgcn_mfma_f32_16x16x32_bf16(k1, qf[1], t, 0, 0, 0);
    }

    bhalf4 pb[4];
#pragma unroll
    for (int n = 0; n < 4; ++n) {
        unsigned a[4];
#pragma unroll
        for (int r = 0; r < 4; ++r) {
            float p = exp2f(s[n][r]);
            if (DIAG) {
                if (16 * n + quad * 4 + r > qloc) p = 0.f;
            }
            a[r] = __float_as_uint(p) + 0x8000u;   // bias-round to bf16
        }
        union { unsigned u[2]; bhalf4 b; } uu;
        uu.u[0] = (a[0] >> 16) | (a[1] & 0xffff0000u);
        uu.u[1] = (a[2] >> 16) | (a[3] & 0xffff0000u);
        pb[n] = uu.b;
        // l-partial on the MFMA pipe: C[*][q] += sum_k P^T[k][q]
        accl = __builtin_amdgcn_mfma_f32_16x16x16bf16_1k(ones, pb[n], accl, 0, 0, 0);
    }

#pragma unroll
    for (int n = 0; n < 4; ++n) {
#pragma unroll
        for (int dt = 0; dt < 4; ++dt) {
            const int d = 16 * dt + col16;
            const bhalf4 av = *(const bhalf4*)&Vt[d * 76 + 16 * n + quad * 4];
            oT[dt] = __builtin_amdgcn_mfma_f32_16x16x16bf16_1k(av, pb[n], oT[dt], 0, 0, 0);
        }
    }
}

__global__ __launch_bounds__(256) void attn_mfma(
    const unsigned short* __restrict__ qkv,
    const unsigned short* __restrict__ vT,
    unsigned short* __restrict__ yout)
{
    __shared__ unsigned short Kbuf[2][64 * 64];
    __shared__ unsigned short Vbuf[2][64 * 76];

    const int tid   = threadIdx.x;
    const int wave  = tid >> 6;
    const int col16 = tid & 15;
    const int quad  = (tid & 63) >> 4;

    // T1 remap: XCD (lin%8) owns logical ids [ (lin%8)*128, +128 ) =
    // heads [4*xcd, 4*xcd+4) x qb 0..31 (longest-first within head).
    const int lin = (int)(blockIdx.y * gridDim.x + blockIdx.x);
    const int swz = (lin & 7) * 128 + (lin >> 3);
    const int qb  = 31 - (swz & 31);
    const int bh  = swz >> 5;
    const int b   = bh >> 4;
    const int h   = bh & 15;

    const unsigned short* base  = qkv + (size_t)b * TSEQ * 3072 + h * 64;
    const unsigned short* kbase = base + CDIM;
    const unsigned short* vtb   = vT + (size_t)(b * 1024 + h * 64) * 2048;

    // Q fragments (B-layout for S^T): lane holds Q[q=wave*16+col16][d=quad*8+j]
    bhalf8 qf[2];
    {
        const unsigned short* qrow =
            base + (size_t)(qb * 64 + wave * 16 + col16) * 3072 + quad * 8;
        qf[0] = *(const bhalf8*)qrow;
        qf[1] = *(const bhalf8*)(qrow + 32);
    }

    // K staging map: lane covers K row (tid>>3)(+32), chunk (tid&7)^(row&7)
    const int krow = tid >> 3;
    const int kchk = (tid & 7) ^ (krow & 7);
    const unsigned short* ksrc0 = kbase + (size_t)krow * 3072 + kchk * 8;
    const unsigned short* ksrc1 = kbase + (size_t)(krow + 32) * 3072 + kchk * 8;

    // V staging map: lane covers vT row d=(tid>>3)(+32), t chunk (tid&7)*8
    const int vd  = tid >> 3;
    const int vt0 = (tid & 7) * 8;
    const unsigned short* vsrc0 = vtb + (size_t)vd * 2048 + vt0;
    const unsigned short* vsrc1 = vtb + (size_t)(vd + 32) * 2048 + vt0;

#define KSTAGE(kb, bf) { \
    char* Kd = (char*)Kbuf[bf] + wave * 1024; \
    async_copy16(ksrc0 + (size_t)(kb) * 64 * 3072, Kd); \
    async_copy16(ksrc1 + (size_t)(kb) * 64 * 3072, Kd + 4096); }

    floatx4 oT[4];
#pragma unroll
    for (int dt = 0; dt < 4; ++dt) oT[dt] = fx4_zero();
    floatx4 accl = fx4_zero();
    const int qloc = wave * 16 + col16;

    {   // prologue: stage tile 0 into buf 0
        uint4 nv0 = *(const uint4*)vsrc0;
        uint4 nv1 = *(const uint4*)vsrc1;
        KSTAGE(0, 0);
        *(uint4*)&Vbuf[0][vd * 76 + vt0]        = nv0;
        *(uint4*)&Vbuf[0][(vd + 32) * 76 + vt0] = nv1;
    }
    __syncthreads();
    int buf = 0;
    for (int kb = 0; kb < qb; ++kb) {
        uint4 nv0 = *(const uint4*)(vsrc0 + (size_t)(kb + 1) * 64);
        uint4 nv1 = *(const uint4*)(vsrc1 + (size_t)(kb + 1) * 64);
        KSTAGE(kb + 1, buf ^ 1);
        attn_tile<false>(Kbuf[buf], Vbuf[buf], qf, oT, accl, col16, quad, qloc);
        *(uint4*)&Vbuf[buf ^ 1][vd * 76 + vt0]        = nv0;
        *(uint4*)&Vbuf[buf ^ 1][(vd + 32) * 76 + vt0] = nv1;
        __syncthreads();
        buf ^= 1;
    }
    attn_tile<true>(Kbuf[buf], Vbuf[buf], qf, oT, accl, col16, quad, qloc);
#undef KSTAGE

    // epilogue: every lane already holds the full l for its q; O^T/l, store
    const float inv = 1.0f / accl[0];
    const size_t row = (size_t)b * TSEQ + (size_t)qb * 64 + wave * 16 + col16;
#pragma unroll
    for (int dt = 0; dt < 4; ++dt) {
        ushort4 o;
        o.x = f2bf(oT[dt][0] * inv);
        o.y = f2bf(oT[dt][1] * inv);
        o.z = f2bf(oT[dt][2] * inv);
        o.w = f2bf(oT[dt][3] * inv);
        *(ushort4*)(yout + row * CDIM + h * 64 + 16 * dt + quad * 4) = o;
    }
}

// ---------------------------------------------------------------------------
extern "C" void kernel_launch(void* const* d_in, const int* in_sizes, int n_in,
                              void* d_out, int out_size, void* d_ws, size_t ws_size,
                              hipStream_t stream)
{
    const float* x      = (const float*)d_in[0];   // [2,2048,1024]
    const float* W_attn = (const float*)d_in[1];   // [1024,3072]
    const float* b_attn = (const float*)d_in[2];   // [3072]
    const float* W_proj = (const float*)d_in[3];   // [1024,1024]
    const float* b_proj = (const float*)d_in[4];   // [1024]
    float* out = (float*)d_out;                    // [2,2048,1024] fp32

    unsigned short* qkv = (unsigned short*)d_ws;             // bf16 [4096,3072] (V third unused)
    unsigned short* y   = qkv + (size_t)4096 * 3072;         // bf16 [4096,1024]
    unsigned short* xb  = y   + (size_t)4096 * 1024;         // bf16 [4096,1024]
    unsigned short* WtA = xb  + (size_t)4096 * 1024;         // bf16 [3072,1024]
    unsigned short* WtP = WtA + (size_t)3072 * 1024;         // bf16 [1024,1024]
    unsigned short* vT  = WtP + (size_t)1024 * 1024;         // bf16 [2048,2048]

    // 0) merged prepass: x->bf16, both weight transposes (one launch)
    prepass<<<dim3(6144), 256, 0, stream>>>(x, xb, W_attn, WtA, W_proj, WtP);

    // 1) qkv = bf16(x @ W_attn + b_attn); Q cols pre-scaled by 0.125*log2e;
    //    V cols (>=2048) transposed to vT.  768 blocks (%8==0, T1 remap)
    gemm_bt<128, 128, true><<<dim3(3072 / 128, 4096 / 128), 256, 0, stream>>>(
        xb, WtA, b_attn, qkv, 4096, 3072, 1024, 2048, vT, 1024);

    // 2) flash attention -> y bf16 [4096,1024]  (v6b + XCD head-chunking)
    attn_mfma<<<dim3(BSZ * HNUM, TSEQ / 64), 256, 0, stream>>>(qkv, vT, y);

    // 3) out = y @ W_proj + b_proj (fp32)  M=4096 N=1024 K=1024.
    //    r2-proven shape: 64x128 tiles, grid 8x64 = 512 blocks (%8==0)
    gemm_bt<64, 128, false><<<dim3(1024 / 128, 4096 / 64), 256, 0, stream>>>(
        y, WtP, b_proj, out, 4096, 1024, 1024, -1, nullptr, 0);
}

// Round 9
// 178.404 us; speedup vs baseline: 1.1613x; 1.1613x over previous
//
#include <hip/hip_runtime.h>
#include <math.h>

#define BSZ 2
#define TSEQ 2048
#define CDIM 1024
#define HNUM 16

typedef __attribute__((ext_vector_type(8))) short bhalf8;
typedef __attribute__((ext_vector_type(4))) short bhalf4;
typedef __attribute__((ext_vector_type(4))) float floatx4;

__device__ __forceinline__ unsigned short f2bf(float f) {
    union { float f; unsigned u; } v;
    v.f = f;
    unsigned r = v.u + 0x7FFFu + ((v.u >> 16) & 1u);
    return (unsigned short)(r >> 16);
}

__device__ __forceinline__ floatx4 fx4_zero() { floatx4 z = {0.f,0.f,0.f,0.f}; return z; }

// async global->LDS, 16 B per lane. lds dest = (wave-uniform base) + lane*16.
typedef __attribute__((address_space(3))) unsigned int lds_u32;
typedef const __attribute__((address_space(1))) unsigned int g_u32;
__device__ __forceinline__ void async_copy16(const void* g, void* l) {
    __builtin_amdgcn_global_load_lds((g_u32*)g, (lds_u32*)l, 16, 0, 0);
}

// ---------------------------------------------------------------------------
// Merged prepass (one launch):
//  blocks [0,2048):    x fp32 -> xb bf16 (8 elems/thread)
//  blocks [2048,5120): W_attn [1024,3072] -> WtA [3072,1024] bf16 transpose
//  blocks [5120,6144): W_proj [1024,1024] -> WtP [1024,1024] bf16 transpose
// ---------------------------------------------------------------------------
__device__ __forceinline__ void trans_tile(
    const float* __restrict__ W, unsigned short* __restrict__ Wt,
    int K, int N, int n0, int k0, int tid, float (*t)[33])
{
    const int tx = tid & 31, ty = tid >> 5;
#pragma unroll
    for (int i = 0; i < 4; ++i)
        t[ty + i * 8][tx] = W[(size_t)(k0 + ty + i * 8) * N + n0 + tx];
    __syncthreads();
#pragma unroll
    for (int i = 0; i < 4; ++i)
        Wt[(size_t)(n0 + ty + i * 8) * K + k0 + tx] = f2bf(t[tx][ty + i * 8]);
}

__global__ __launch_bounds__(256) void prepass(
    const float* __restrict__ x, unsigned short* __restrict__ xb,
    const float* __restrict__ Wa, unsigned short* __restrict__ WtA,
    const float* __restrict__ Wp, unsigned short* __restrict__ WtP)
{
    __shared__ float t[32][33];
    const int bid = blockIdx.x;
    const int tid = threadIdx.x;
    if (bid < 2048) {
        size_t i = ((size_t)bid * 256 + tid) * 8;
        float4 a = *(const float4*)(x + i);
        float4 b = *(const float4*)(x + i + 4);
        uint4 o;
        o.x = (unsigned)f2bf(a.x) | ((unsigned)f2bf(a.y) << 16);
        o.y = (unsigned)f2bf(a.z) | ((unsigned)f2bf(a.w) << 16);
        o.z = (unsigned)f2bf(b.x) | ((unsigned)f2bf(b.y) << 16);
        o.w = (unsigned)f2bf(b.z) | ((unsigned)f2bf(b.w) << 16);
        *(uint4*)(xb + i) = o;
    } else if (bid < 5120) {
        int tl = bid - 2048;                       // 96 n-tiles x 32 k-tiles
        trans_tile(Wa, WtA, 1024, 3072, (tl % 96) * 32, (tl / 96) * 32, tid, t);
    } else {
        int tl = bid - 5120;                       // 32 x 32
        trans_tile(Wp, WtP, 1024, 1024, (tl % 32) * 32, (tl / 32) * 32, tid, t);
    }
}

// ---------------------------------------------------------------------------
// bf16 MFMA GEMM (B^T input) + bias, single-barrier double-buffered K-loop.
// C[M,N] = A[M,K] @ Bt[N,K]^T + bias[N].  Block tile BM x BN, BK=32,
// 256 threads (4 waves). Wave covers (BM/2)x(BN/2); acc = MTxNT of 16x16.
// T1 XCD remap (uniform-work GEMM only; REFUTED for causal attn, r8):
// swz = (L%8)*(nwg/8) + L/8, bn-fastest chunk per XCD. nwg%8==0 holds.
// T2 LDS chunk swizzle: data (row r, k-chunk q) at slot (q+(r>>1))&3;
// staged via pre-swizzled GLOBAL source, read with sw8 (conflict-free).
// Blocks whose colbase >= v_start write TRANSPOSED to vt via ushort4.
// Columns < q_end get scaled by 0.125*log2(e) in fp32 before bf16 round.
// ---------------------------------------------------------------------------
template<int BM, int BN, bool OUT_BF16>
__global__ __launch_bounds__(256) void gemm_bt(
    const unsigned short* __restrict__ A, const unsigned short* __restrict__ Bt,
    const float* __restrict__ bias, void* __restrict__ Cp,
    int M, int N, int K, int v_start, unsigned short* __restrict__ vt, int q_end)
{
    constexpr int ALINES = BM / 64;
    constexpr int BLINES = BN / 64;
    constexpr int MT = BM / 32;
    constexpr int NT = BN / 32;
    __shared__ unsigned short As[2][BM * 32];
    __shared__ unsigned short Bs[2][BN * 32];

    const int tid   = threadIdx.x;
    // XCD-aware block remap (bijective: nwg % 8 == 0 for all launches)
    const int nx  = (int)gridDim.x;
    const int lin = (int)(blockIdx.y * gridDim.x + blockIdx.x);
    const int cpx = (int)(gridDim.x * gridDim.y) >> 3;
    const int swz = (lin & 7) * cpx + (lin >> 3);
    const int bn  = swz % nx;
    const int bm  = swz / nx;

    const int wave  = tid >> 6;
    const int col16 = tid & 15;
    const int quad  = (tid & 63) >> 4;
    const int wm    = (wave >> 1) * (BM / 2);
    const int wn    = (wave & 1) * (BN / 2);

    floatx4 acc[MT][NT];
#pragma unroll
    for (int i = 0; i < MT; ++i)
#pragma unroll
        for (int j = 0; j < NT; ++j) acc[i][j] = fx4_zero();

    // staging: lane covers row gr, global k-chunk pre-swizzled so that LDS
    // slot (gr, tid&3) holds chunk ((tid&3) - (gr>>1)) & 3
    const int gr = tid >> 2;
    const int gk = (((tid & 3) + 4 - ((tid >> 3) & 3)) & 3) * 8;
    const unsigned short* Ab = A  + (size_t)(bm * BM + gr) * K + gk;
    const unsigned short* Bb = Bt + (size_t)(bn * BN + gr) * K + gk;

    // fragment read: slot of k-chunk `quad` for row (.. + col16)
    const int sw8 = ((quad + (col16 >> 1)) & 3) * 8;

#define STAGE(k0, bf) { \
    char* AsB = (char*)As[bf] + wave * 1024; \
    char* BsB = (char*)Bs[bf] + wave * 1024; \
    _Pragma("unroll") \
    for (int l = 0; l < ALINES; ++l) \
        async_copy16(Ab + (size_t)l * 64 * K + (k0), AsB + l * 4096); \
    _Pragma("unroll") \
    for (int l = 0; l < BLINES; ++l) \
        async_copy16(Bb + (size_t)l * 64 * K + (k0), BsB + l * 4096); }

#define COMPUTE(bf) { \
    bhalf8 a[MT], b[NT]; \
    _Pragma("unroll") \
    for (int i = 0; i < MT; ++i) \
        a[i] = *(const bhalf8*)&As[bf][(wm + i * 16 + col16) * 32 + sw8]; \
    _Pragma("unroll") \
    for (int j = 0; j < NT; ++j) \
        b[j] = *(const bhalf8*)&Bs[bf][(wn + j * 16 + col16) * 32 + sw8]; \
    _Pragma("unroll") \
    for (int i = 0; i < MT; ++i) \
        _Pragma("unroll") \
        for (int j = 0; j < NT; ++j) \
            acc[i][j] = __builtin_amdgcn_mfma_f32_16x16x32_bf16(a[i], b[j], acc[i][j], 0, 0, 0); }

    STAGE(0, 0);
    __syncthreads();
    int buf = 0;
    for (int k0 = 0; k0 < K - 32; k0 += 32) {
        STAGE(k0 + 32, buf ^ 1);
        COMPUTE(buf);
        __syncthreads();
        buf ^= 1;
    }
    COMPUTE(buf);
#undef STAGE
#undef COMPUTE

    const int colbase = bn * BN + wn;
    const bool vpath = (v_start >= 0) && (colbase >= v_start);  // wave-uniform
    const float csc = (colbase < q_end) ? 0.18033688f : 1.0f;   // wave-uniform
#pragma unroll
    for (int j = 0; j < NT; ++j) {
        int col = colbase + j * 16 + col16;
        float bv = bias[col];
#pragma unroll
        for (int i = 0; i < MT; ++i) {
            if (vpath) {
                int row0 = bm * BM + wm + i * 16 + quad * 4;
                ushort4 o;
                o.x = f2bf((acc[i][j][0] + bv) * csc);
                o.y = f2bf((acc[i][j][1] + bv) * csc);
                o.z = f2bf((acc[i][j][2] + bv) * csc);
                o.w = f2bf((acc[i][j][3] + bv) * csc);
                size_t vrow = (size_t)((row0 >> 11) * 1024 + (col - v_start));
                *(ushort4*)(vt + vrow * 2048 + (row0 & 2047)) = o;
            } else {
#pragma unroll
                for (int r = 0; r < 4; ++r) {
                    int row = bm * BM + wm + i * 16 + quad * 4 + r;
                    float v = (acc[i][j][r] + bv) * csc;
                    if (OUT_BF16)
                        ((unsigned short*)Cp)[(size_t)row * N + col] = f2bf(v);
                    else
                        ((float*)Cp)[(size_t)row * N + col] = v;
                }
            }
        }
    }
}

// ---------------------------------------------------------------------------
// MFMA flash attention v6b (r2/r5-proven, 45.3 us): transposed scores, P in
// registers, double-buffered single-barrier KV loop.
//   S^T = K.Q^T (16x16x32);  O^T = V^T.P^T (16x16x16, P^T direct from regs)
// Q pre-scaled by 0.125*log2e (folded into GEMM-1); -17.312 shift folded
// into the QK^T accumulator init; softmax inner loop = exp2 + bit-pack.
// l accumulated on the MFMA pipe as ones^T.P^T (no epilogue shuffle).
// REFUTED levers (do not re-apply): split-acc+setprio (r4, +4 us);
// QBLK=128/512thr (r6/r7, +6..11 us); XCD head-chunk remap (r8, +30 us --
// causal work imbalance: co-resident chunk correlates qb per CU).
// K image:  row*128B + (chunk ^ (row&7))*16B   (async-staged; b128 reads
//   conflict-free). V image: Vt[d*76 + t]; PV b64 read phase bank start
//   = 6*col16 -> conflict-free.
// ---------------------------------------------------------------------------
template<bool DIAG>
__device__ __forceinline__ void attn_tile(
    const unsigned short* __restrict__ Ks, const unsigned short* __restrict__ Vt,
    const bhalf8* qf, floatx4* oT, floatx4& accl,
    int col16, int quad, int qloc)
{
    const int sx = col16 & 7;
    const floatx4 minusC = {-17.31234049f, -17.31234049f, -17.31234049f, -17.31234049f};
    const bhalf4 ones = {0x3F80, 0x3F80, 0x3F80, 0x3F80};   // bf16 1.0 x4

    floatx4 s[4];
#pragma unroll
    for (int n = 0; n < 4; ++n) {
        const int row = 16 * n + col16;
        bhalf8 k0 = *(const bhalf8*)&Ks[row * 64 + ((quad ^ sx) * 8)];
        bhalf8 k1 = *(const bhalf8*)&Ks[row * 64 + (((4 + quad) ^ sx) * 8)];
        floatx4 t = __builtin_amdgcn_mfma_f32_16x16x32_bf16(k0, qf[0], minusC, 0, 0, 0);
        s[n] = __builtin_amdgcn_mfma_f32_16x16x32_bf16(k1, qf[1], t, 0, 0, 0);
    }

    bhalf4 pb[4];
#pragma unroll
    for (int n = 0; n < 4; ++n) {
        unsigned a[4];
#pragma unroll
        for (int r = 0; r < 4; ++r) {
            float p = exp2f(s[n][r]);
            if (DIAG) {
                if (16 * n + quad * 4 + r > qloc) p = 0.f;
            }
            a[r] = __float_as_uint(p) + 0x8000u;   // bias-round to bf16
        }
        union { unsigned u[2]; bhalf4 b; } uu;
        uu.u[0] = (a[0] >> 16) | (a[1] & 0xffff0000u);
        uu.u[1] = (a[2] >> 16) | (a[3] & 0xffff0000u);
        pb[n] = uu.b;
        // l-partial on the MFMA pipe: C[*][q] += sum_k P^T[k][q]
        accl = __builtin_amdgcn_mfma_f32_16x16x16bf16_1k(ones, pb[n], accl, 0, 0, 0);
    }

#pragma unroll
    for (int n = 0; n < 4; ++n) {
#pragma unroll
        for (int dt = 0; dt < 4; ++dt) {
            const int d = 16 * dt + col16;
            const bhalf4 av = *(const bhalf4*)&Vt[d * 76 + 16 * n + quad * 4];
            oT[dt] = __builtin_amdgcn_mfma_f32_16x16x16bf16_1k(av, pb[n], oT[dt], 0, 0, 0);
        }
    }
}

__global__ __launch_bounds__(256) void attn_mfma(
    const unsigned short* __restrict__ qkv,
    const unsigned short* __restrict__ vT,
    unsigned short* __restrict__ yout)
{
    __shared__ unsigned short Kbuf[2][64 * 64];
    __shared__ unsigned short Vbuf[2][64 * 76];

    const int tid   = threadIdx.x;
    const int wave  = tid >> 6;
    const int col16 = tid & 15;
    const int quad  = (tid & 63) >> 4;
    const int qb    = (int)gridDim.y - 1 - (int)blockIdx.y;  // longest first
    const int bh    = blockIdx.x;
    const int b     = bh >> 4;
    const int h     = bh & 15;

    const unsigned short* base  = qkv + (size_t)b * TSEQ * 3072 + h * 64;
    const unsigned short* kbase = base + CDIM;
    const unsigned short* vtb   = vT + (size_t)(b * 1024 + h * 64) * 2048;

    // Q fragments (B-layout for S^T): lane holds Q[q=wave*16+col16][d=quad*8+j]
    bhalf8 qf[2];
    {
        const unsigned short* qrow =
            base + (size_t)(qb * 64 + wave * 16 + col16) * 3072 + quad * 8;
        qf[0] = *(const bhalf8*)qrow;
        qf[1] = *(const bhalf8*)(qrow + 32);
    }

    // K staging map: lane covers K row (tid>>3)(+32), chunk (tid&7)^(row&7)
    const int krow = tid >> 3;
    const int kchk = (tid & 7) ^ (krow & 7);
    const unsigned short* ksrc0 = kbase + (size_t)krow * 3072 + kchk * 8;
    const unsigned short* ksrc1 = kbase + (size_t)(krow + 32) * 3072 + kchk * 8;

    // V staging map: lane covers vT row d=(tid>>3)(+32), t chunk (tid&7)*8
    const int vd  = tid >> 3;
    const int vt0 = (tid & 7) * 8;
    const unsigned short* vsrc0 = vtb + (size_t)vd * 2048 + vt0;
    const unsigned short* vsrc1 = vtb + (size_t)(vd + 32) * 2048 + vt0;

#define KSTAGE(kb, bf) { \
    char* Kd = (char*)Kbuf[bf] + wave * 1024; \
    async_copy16(ksrc0 + (size_t)(kb) * 64 * 3072, Kd); \
    async_copy16(ksrc1 + (size_t)(kb) * 64 * 3072, Kd + 4096); }

    floatx4 oT[4];
#pragma unroll
    for (int dt = 0; dt < 4; ++dt) oT[dt] = fx4_zero();
    floatx4 accl = fx4_zero();
    const int qloc = wave * 16 + col16;

    {   // prologue: stage tile 0 into buf 0
        uint4 nv0 = *(const uint4*)vsrc0;
        uint4 nv1 = *(const uint4*)vsrc1;
        KSTAGE(0, 0);
        *(uint4*)&Vbuf[0][vd * 76 + vt0]        = nv0;
        *(uint4*)&Vbuf[0][(vd + 32) * 76 + vt0] = nv1;
    }
    __syncthreads();
    int buf = 0;
    for (int kb = 0; kb < qb; ++kb) {
        uint4 nv0 = *(const uint4*)(vsrc0 + (size_t)(kb + 1) * 64);
        uint4 nv1 = *(const uint4*)(vsrc1 + (size_t)(kb + 1) * 64);
        KSTAGE(kb + 1, buf ^ 1);
        attn_tile<false>(Kbuf[buf], Vbuf[buf], qf, oT, accl, col16, quad, qloc);
        *(uint4*)&Vbuf[buf ^ 1][vd * 76 + vt0]        = nv0;
        *(uint4*)&Vbuf[buf ^ 1][(vd + 32) * 76 + vt0] = nv1;
        __syncthreads();
        buf ^= 1;
    }
    attn_tile<true>(Kbuf[buf], Vbuf[buf], qf, oT, accl, col16, quad, qloc);
#undef KSTAGE

    // epilogue: every lane already holds the full l for its q; O^T/l, store
    const float inv = 1.0f / accl[0];
    const size_t row = (size_t)b * TSEQ + (size_t)qb * 64 + wave * 16 + col16;
#pragma unroll
    for (int dt = 0; dt < 4; ++dt) {
        ushort4 o;
        o.x = f2bf(oT[dt][0] * inv);
        o.y = f2bf(oT[dt][1] * inv);
        o.z = f2bf(oT[dt][2] * inv);
        o.w = f2bf(oT[dt][3] * inv);
        *(ushort4*)(yout + row * CDIM + h * 64 + 16 * dt + quad * 4) = o;
    }
}

// ---------------------------------------------------------------------------
extern "C" void kernel_launch(void* const* d_in, const int* in_sizes, int n_in,
                              void* d_out, int out_size, void* d_ws, size_t ws_size,
                              hipStream_t stream)
{
    const float* x      = (const float*)d_in[0];   // [2,2048,1024]
    const float* W_attn = (const float*)d_in[1];   // [1024,3072]
    const float* b_attn = (const float*)d_in[2];   // [3072]
    const float* W_proj = (const float*)d_in[3];   // [1024,1024]
    const float* b_proj = (const float*)d_in[4];   // [1024]
    float* out = (float*)d_out;                    // [2,2048,1024] fp32

    unsigned short* qkv = (unsigned short*)d_ws;             // bf16 [4096,3072] (V third unused)
    unsigned short* y   = qkv + (size_t)4096 * 3072;         // bf16 [4096,1024]
    unsigned short* xb  = y   + (size_t)4096 * 1024;         // bf16 [4096,1024]
    unsigned short* WtA = xb  + (size_t)4096 * 1024;         // bf16 [3072,1024]
    unsigned short* WtP = WtA + (size_t)3072 * 1024;         // bf16 [1024,1024]
    unsigned short* vT  = WtP + (size_t)1024 * 1024;         // bf16 [2048,2048]

    // 0) merged prepass: x->bf16, both weight transposes (one launch)
    prepass<<<dim3(6144), 256, 0, stream>>>(x, xb, W_attn, WtA, W_proj, WtP);

    // 1) qkv = bf16(x @ W_attn + b_attn); Q cols pre-scaled by 0.125*log2e;
    //    V cols (>=2048) transposed to vT.  768 blocks (%8==0, T1 remap)
    gemm_bt<128, 128, true><<<dim3(3072 / 128, 4096 / 128), 256, 0, stream>>>(
        xb, WtA, b_attn, qkv, 4096, 3072, 1024, 2048, vT, 1024);

    // 2) flash attention -> y bf16 [4096,1024]  (v6b, default dispatch order)
    attn_mfma<<<dim3(BSZ * HNUM, TSEQ / 64), 256, 0, stream>>>(qkv, vT, y);

    // 3) out = y @ W_proj + b_proj (fp32)  M=4096 N=1024 K=1024.
    //    r2-proven shape: 64x128 tiles, grid 8x64 = 512 blocks (%8==0)
    gemm_bt<64, 128, false><<<dim3(1024 / 128, 4096 / 64), 256, 0, stream>>>(
        y, WtP, b_proj, out, 4096, 1024, 1024, -1, nullptr, 0);
}

// Round 10
// 177.326 us; speedup vs baseline: 1.1684x; 1.0061x over previous
//
#include <hip/hip_runtime.h>
#include <math.h>

#define BSZ 2
#define TSEQ 2048
#define CDIM 1024
#define HNUM 16

typedef __attribute__((ext_vector_type(8))) short bhalf8;
typedef __attribute__((ext_vector_type(4))) short bhalf4;
typedef __attribute__((ext_vector_type(4))) float floatx4;

__device__ __forceinline__ unsigned short f2bf(float f) {
    union { float f; unsigned u; } v;
    v.f = f;
    unsigned r = v.u + 0x7FFFu + ((v.u >> 16) & 1u);
    return (unsigned short)(r >> 16);
}

__device__ __forceinline__ floatx4 fx4_zero() { floatx4 z = {0.f,0.f,0.f,0.f}; return z; }

// async global->LDS, 16 B per lane. lds dest = (wave-uniform base) + lane*16.
typedef __attribute__((address_space(3))) unsigned int lds_u32;
typedef const __attribute__((address_space(1))) unsigned int g_u32;
__device__ __forceinline__ void async_copy16(const void* g, void* l) {
    __builtin_amdgcn_global_load_lds((g_u32*)g, (lds_u32*)l, 16, 0, 0);
}

// ---------------------------------------------------------------------------
// Merged prepass (one launch):
//  blocks [0,2048):    x fp32 -> xb bf16 (8 elems/thread)
//  blocks [2048,5120): W_attn [1024,3072] -> WtA [3072,1024] bf16 transpose
//  blocks [5120,6144): W_proj [1024,1024] -> WtP [1024,1024] bf16 transpose
// ---------------------------------------------------------------------------
__device__ __forceinline__ void trans_tile(
    const float* __restrict__ W, unsigned short* __restrict__ Wt,
    int K, int N, int n0, int k0, int tid, float (*t)[33])
{
    const int tx = tid & 31, ty = tid >> 5;
#pragma unroll
    for (int i = 0; i < 4; ++i)
        t[ty + i * 8][tx] = W[(size_t)(k0 + ty + i * 8) * N + n0 + tx];
    __syncthreads();
#pragma unroll
    for (int i = 0; i < 4; ++i)
        Wt[(size_t)(n0 + ty + i * 8) * K + k0 + tx] = f2bf(t[tx][ty + i * 8]);
}

__global__ __launch_bounds__(256) void prepass(
    const float* __restrict__ x, unsigned short* __restrict__ xb,
    const float* __restrict__ Wa, unsigned short* __restrict__ WtA,
    const float* __restrict__ Wp, unsigned short* __restrict__ WtP)
{
    __shared__ float t[32][33];
    const int bid = blockIdx.x;
    const int tid = threadIdx.x;
    if (bid < 2048) {
        size_t i = ((size_t)bid * 256 + tid) * 8;
        float4 a = *(const float4*)(x + i);
        float4 b = *(const float4*)(x + i + 4);
        uint4 o;
        o.x = (unsigned)f2bf(a.x) | ((unsigned)f2bf(a.y) << 16);
        o.y = (unsigned)f2bf(a.z) | ((unsigned)f2bf(a.w) << 16);
        o.z = (unsigned)f2bf(b.x) | ((unsigned)f2bf(b.y) << 16);
        o.w = (unsigned)f2bf(b.z) | ((unsigned)f2bf(b.w) << 16);
        *(uint4*)(xb + i) = o;
    } else if (bid < 5120) {
        int tl = bid - 2048;                       // 96 n-tiles x 32 k-tiles
        trans_tile(Wa, WtA, 1024, 3072, (tl % 96) * 32, (tl / 96) * 32, tid, t);
    } else {
        int tl = bid - 5120;                       // 32 x 32
        trans_tile(Wp, WtP, 1024, 1024, (tl % 32) * 32, (tl / 32) * 32, tid, t);
    }
}

// ---------------------------------------------------------------------------
// bf16 MFMA GEMM (B^T input) + bias, single-barrier double-buffered K-loop.
// C[M,N] = A[M,K] @ Bt[N,K]^T + bias[N].  Block tile BM x BN, K-step BK,
// 256 threads (4 waves). Wave covers (BM/2)x(BN/2); acc = MTxNT of 16x16.
// T1 XCD remap (uniform-work GEMM only; REFUTED for causal attn, r8):
// swz = (L%8)*(nwg/8) + L/8, bn-fastest chunk per XCD. nwg%8==0 holds.
// LDS swizzles (T2, both-sides: pre-swizzled GLOBAL source + swizzled read,
// LDS dest linear for global_load_lds):
//  BK=32 (row=64B): slot c = (q + (r>>1)) & 3; read sw8=((quad+(col16>>1))&3)*8
//  BK=64 (row=128B = exact bank wrap, would be 8-way conflicted linear):
//    slot c = q ^ (r&7); read chunk (kk*4+quad) ^ (col16&7) -> each 8-lane
//    phase covers all 32 banks once (attn-K-proven pattern).
// BK=64 halves the barrier count for short-K GEMMs (gemm3: 32 -> 16 steps,
// 16 MFMA/wave/step) -- the drain-dominated regime fix.  gemm1 stays BK=32
// (BK=64 would cut its occupancy 4->2 blocks/CU per LDS; m132 lesson).
// Blocks whose colbase >= v_start write TRANSPOSED to vt via ushort4.
// Columns < q_end get scaled by 0.125*log2(e) in fp32 before bf16 round.
// ---------------------------------------------------------------------------
template<int BM, int BN, int BK, bool OUT_BF16>
__global__ __launch_bounds__(256) void gemm_bt(
    const unsigned short* __restrict__ A, const unsigned short* __restrict__ Bt,
    const float* __restrict__ bias, void* __restrict__ Cp,
    int M, int N, int K, int v_start, unsigned short* __restrict__ vt, int q_end)
{
    constexpr int ALINES = (BM * BK) / 2048;   // 256 lanes x 8 shorts per line
    constexpr int BLINES = (BN * BK) / 2048;
    constexpr int MT = BM / 32;
    constexpr int NT = BN / 32;
    constexpr int KK = BK / 32;                 // k-chunks of 32 per step
    constexpr int CPR = BK / 8;                 // 16B-chunks per row
    __shared__ unsigned short As[2][BM * BK];
    __shared__ unsigned short Bs[2][BN * BK];

    const int tid   = threadIdx.x;
    // XCD-aware block remap (bijective: nwg % 8 == 0 for all launches)
    const int nx  = (int)gridDim.x;
    const int lin = (int)(blockIdx.y * gridDim.x + blockIdx.x);
    const int cpx = (int)(gridDim.x * gridDim.y) >> 3;
    const int swz = (lin & 7) * cpx + (lin >> 3);
    const int bn  = swz % nx;
    const int bm  = swz / nx;

    const int wave  = tid >> 6;
    const int col16 = tid & 15;
    const int quad  = (tid & 63) >> 4;
    const int wm    = (wave >> 1) * (BM / 2);
    const int wn    = (wave & 1) * (BN / 2);

    floatx4 acc[MT][NT];
#pragma unroll
    for (int i = 0; i < MT; ++i)
#pragma unroll
        for (int j = 0; j < NT; ++j) acc[i][j] = fx4_zero();

    // staging: lane covers row gr, global k-chunk pre-swizzled per BK scheme
    const int gr = tid / CPR;
    const int cq = tid % CPR;
    const int gk = (BK == 32)
        ? (((cq + 4 - ((gr >> 1) & 3)) & 3) * 8)
        : ((cq ^ (gr & 7)) * 8);
    const unsigned short* Ab = A  + (size_t)(bm * BM + gr) * K + gk;
    const unsigned short* Bb = Bt + (size_t)(bn * BN + gr) * K + gk;
    constexpr int RPL = 2048 / BK;              // rows per staged line

#define STAGE(k0, bf) { \
    char* AsB = (char*)As[bf] + wave * 1024; \
    char* BsB = (char*)Bs[bf] + wave * 1024; \
    _Pragma("unroll") \
    for (int l = 0; l < ALINES; ++l) \
        async_copy16(Ab + (size_t)l * RPL * K + (k0), AsB + l * 4096); \
    _Pragma("unroll") \
    for (int l = 0; l < BLINES; ++l) \
        async_copy16(Bb + (size_t)l * RPL * K + (k0), BsB + l * 4096); }

#define COMPUTE(bf) { \
    _Pragma("unroll") \
    for (int kk = 0; kk < KK; ++kk) { \
        const int sw8 = (BK == 32) \
            ? (((quad + (col16 >> 1)) & 3) * 8) \
            : ((((kk << 2) + quad) ^ (col16 & 7)) * 8); \
        bhalf8 a[MT], b[NT]; \
        _Pragma("unroll") \
        for (int i = 0; i < MT; ++i) \
            a[i] = *(const bhalf8*)&As[bf][(wm + i * 16 + col16) * BK + sw8]; \
        _Pragma("unroll") \
        for (int j = 0; j < NT; ++j) \
            b[j] = *(const bhalf8*)&Bs[bf][(wn + j * 16 + col16) * BK + sw8]; \
        _Pragma("unroll") \
        for (int i = 0; i < MT; ++i) \
            _Pragma("unroll") \
            for (int j = 0; j < NT; ++j) \
                acc[i][j] = __builtin_amdgcn_mfma_f32_16x16x32_bf16(a[i], b[j], acc[i][j], 0, 0, 0); \
    } }

    STAGE(0, 0);
    __syncthreads();
    int buf = 0;
    for (int k0 = 0; k0 < K - BK; k0 += BK) {
        STAGE(k0 + BK, buf ^ 1);
        COMPUTE(buf);
        __syncthreads();
        buf ^= 1;
    }
    COMPUTE(buf);
#undef STAGE
#undef COMPUTE

    const int colbase = bn * BN + wn;
    const bool vpath = (v_start >= 0) && (colbase >= v_start);  // wave-uniform
    const float csc = (colbase < q_end) ? 0.18033688f : 1.0f;   // wave-uniform
#pragma unroll
    for (int j = 0; j < NT; ++j) {
        int col = colbase + j * 16 + col16;
        float bv = bias[col];
#pragma unroll
        for (int i = 0; i < MT; ++i) {
            if (vpath) {
                int row0 = bm * BM + wm + i * 16 + quad * 4;
                ushort4 o;
                o.x = f2bf((acc[i][j][0] + bv) * csc);
                o.y = f2bf((acc[i][j][1] + bv) * csc);
                o.z = f2bf((acc[i][j][2] + bv) * csc);
                o.w = f2bf((acc[i][j][3] + bv) * csc);
                size_t vrow = (size_t)((row0 >> 11) * 1024 + (col - v_start));
                *(ushort4*)(vt + vrow * 2048 + (row0 & 2047)) = o;
            } else {
#pragma unroll
                for (int r = 0; r < 4; ++r) {
                    int row = bm * BM + wm + i * 16 + quad * 4 + r;
                    float v = (acc[i][j][r] + bv) * csc;
                    if (OUT_BF16)
                        ((unsigned short*)Cp)[(size_t)row * N + col] = f2bf(v);
                    else
                        ((float*)Cp)[(size_t)row * N + col] = v;
                }
            }
        }
    }
}

// ---------------------------------------------------------------------------
// MFMA flash attention v6b (r2/r5/r9-proven, 45.5 us): transposed scores, P
// in registers, double-buffered single-barrier KV loop.
//   S^T = K.Q^T (16x16x32);  O^T = V^T.P^T (16x16x16, P^T direct from regs)
// Q pre-scaled by 0.125*log2e (folded into GEMM-1); -17.312 shift folded
// into the QK^T accumulator init; softmax inner loop = exp2 + bit-pack.
// l accumulated on the MFMA pipe as ones^T.P^T (no epilogue shuffle).
// REFUTED levers (do not re-apply): split-acc+setprio (r4, +4 us);
// QBLK=128/512thr (r6/r7, +6..11 us); XCD head-chunk remap (r8, +30 us --
// causal work imbalance: co-resident chunk correlates qb per CU).
// K image:  row*128B + (chunk ^ (row&7))*16B   (async-staged; b128 reads
//   conflict-free). V image: Vt[d*76 + t]; PV b64 read phase bank start
//   = 6*col16 -> conflict-free.
// ---------------------------------------------------------------------------
template<bool DIAG>
__device__ __forceinline__ void attn_tile(
    const unsigned short* __restrict__ Ks, const unsigned short* __restrict__ Vt,
    const bhalf8* qf, floatx4* oT, floatx4& accl,
    int col16, int quad, int qloc)
{
    const int sx = col16 & 7;
    const floatx4 minusC = {-17.31234049f, -17.31234049f, -17.31234049f, -17.31234049f};
    const bhalf4 ones = {0x3F80, 0x3F80, 0x3F80, 0x3F80};   // bf16 1.0 x4

    floatx4 s[4];
#pragma unroll
    for (int n = 0; n < 4; ++n) {
        const int row = 16 * n + col16;
        bhalf8 k0 = *(const bhalf8*)&Ks[row * 64 + ((quad ^ sx) * 8)];
        bhalf8 k1 = *(const bhalf8*)&Ks[row * 64 + (((4 + quad) ^ sx) * 8)];
        floatx4 t = __builtin_amdgcn_mfma_f32_16x16x32_bf16(k0, qf[0], minusC, 0, 0, 0);
        s[n] = __builtin_amdgcn_mfma_f32_16x16x32_bf16(k1, qf[1], t, 0, 0, 0);
    }

    bhalf4 pb[4];
#pragma unroll
    for (int n = 0; n < 4; ++n) {
        unsigned a[4];
#pragma unroll
        for (int r = 0; r < 4; ++r) {
            float p = exp2f(s[n][r]);
            if (DIAG) {
                if (16 * n + quad * 4 + r > qloc) p = 0.f;
            }
            a[r] = __float_as_uint(p) + 0x8000u;   // bias-round to bf16
        }
        union { unsigned u[2]; bhalf4 b; } uu;
        uu.u[0] = (a[0] >> 16) | (a[1] & 0xffff0000u);
        uu.u[1] = (a[2] >> 16) | (a[3] & 0xffff0000u);
        pb[n] = uu.b;
        // l-partial on the MFMA pipe: C[*][q] += sum_k P^T[k][q]
        accl = __builtin_amdgcn_mfma_f32_16x16x16bf16_1k(ones, pb[n], accl, 0, 0, 0);
    }

#pragma unroll
    for (int n = 0; n < 4; ++n) {
#pragma unroll
        for (int dt = 0; dt < 4; ++dt) {
            const int d = 16 * dt + col16;
            const bhalf4 av = *(const bhalf4*)&Vt[d * 76 + 16 * n + quad * 4];
            oT[dt] = __builtin_amdgcn_mfma_f32_16x16x16bf16_1k(av, pb[n], oT[dt], 0, 0, 0);
        }
    }
}

__global__ __launch_bounds__(256) void attn_mfma(
    const unsigned short* __restrict__ qkv,
    const unsigned short* __restrict__ vT,
    unsigned short* __restrict__ yout)
{
    __shared__ unsigned short Kbuf[2][64 * 64];
    __shared__ unsigned short Vbuf[2][64 * 76];

    const int tid   = threadIdx.x;
    const int wave  = tid >> 6;
    const int col16 = tid & 15;
    const int quad  = (tid & 63) >> 4;
    const int qb    = (int)gridDim.y - 1 - (int)blockIdx.y;  // longest first
    const int bh    = blockIdx.x;
    const int b     = bh >> 4;
    const int h     = bh & 15;

    const unsigned short* base  = qkv + (size_t)b * TSEQ * 3072 + h * 64;
    const unsigned short* kbase = base + CDIM;
    const unsigned short* vtb   = vT + (size_t)(b * 1024 + h * 64) * 2048;

    // Q fragments (B-layout for S^T): lane holds Q[q=wave*16+col16][d=quad*8+j]
    bhalf8 qf[2];
    {
        const unsigned short* qrow =
            base + (size_t)(qb * 64 + wave * 16 + col16) * 3072 + quad * 8;
        qf[0] = *(const bhalf8*)qrow;
        qf[1] = *(const bhalf8*)(qrow + 32);
    }

    // K staging map: lane covers K row (tid>>3)(+32), chunk (tid&7)^(row&7)
    const int krow = tid >> 3;
    const int kchk = (tid & 7) ^ (krow & 7);
    const unsigned short* ksrc0 = kbase + (size_t)krow * 3072 + kchk * 8;
    const unsigned short* ksrc1 = kbase + (size_t)(krow + 32) * 3072 + kchk * 8;

    // V staging map: lane covers vT row d=(tid>>3)(+32), t chunk (tid&7)*8
    const int vd  = tid >> 3;
    const int vt0 = (tid & 7) * 8;
    const unsigned short* vsrc0 = vtb + (size_t)vd * 2048 + vt0;
    const unsigned short* vsrc1 = vtb + (size_t)(vd + 32) * 2048 + vt0;

#define KSTAGE(kb, bf) { \
    char* Kd = (char*)Kbuf[bf] + wave * 1024; \
    async_copy16(ksrc0 + (size_t)(kb) * 64 * 3072, Kd); \
    async_copy16(ksrc1 + (size_t)(kb) * 64 * 3072, Kd + 4096); }

    floatx4 oT[4];
#pragma unroll
    for (int dt = 0; dt < 4; ++dt) oT[dt] = fx4_zero();
    floatx4 accl = fx4_zero();
    const int qloc = wave * 16 + col16;

    {   // prologue: stage tile 0 into buf 0
        uint4 nv0 = *(const uint4*)vsrc0;
        uint4 nv1 = *(const uint4*)vsrc1;
        KSTAGE(0, 0);
        *(uint4*)&Vbuf[0][vd * 76 + vt0]        = nv0;
        *(uint4*)&Vbuf[0][(vd + 32) * 76 + vt0] = nv1;
    }
    __syncthreads();
    int buf = 0;
    for (int kb = 0; kb < qb; ++kb) {
        uint4 nv0 = *(const uint4*)(vsrc0 + (size_t)(kb + 1) * 64);
        uint4 nv1 = *(const uint4*)(vsrc1 + (size_t)(kb + 1) * 64);
        KSTAGE(kb + 1, buf ^ 1);
        attn_tile<false>(Kbuf[buf], Vbuf[buf], qf, oT, accl, col16, quad, qloc);
        *(uint4*)&Vbuf[buf ^ 1][vd * 76 + vt0]        = nv0;
        *(uint4*)&Vbuf[buf ^ 1][(vd + 32) * 76 + vt0] = nv1;
        __syncthreads();
        buf ^= 1;
    }
    attn_tile<true>(Kbuf[buf], Vbuf[buf], qf, oT, accl, col16, quad, qloc);
#undef KSTAGE

    // epilogue: every lane already holds the full l for its q; O^T/l, store
    const float inv = 1.0f / accl[0];
    const size_t row = (size_t)b * TSEQ + (size_t)qb * 64 + wave * 16 + col16;
#pragma unroll
    for (int dt = 0; dt < 4; ++dt) {
        ushort4 o;
        o.x = f2bf(oT[dt][0] * inv);
        o.y = f2bf(oT[dt][1] * inv);
        o.z = f2bf(oT[dt][2] * inv);
        o.w = f2bf(oT[dt][3] * inv);
        *(ushort4*)(yout + row * CDIM + h * 64 + 16 * dt + quad * 4) = o;
    }
}

// ---------------------------------------------------------------------------
extern "C" void kernel_launch(void* const* d_in, const int* in_sizes, int n_in,
                              void* d_out, int out_size, void* d_ws, size_t ws_size,
                              hipStream_t stream)
{
    const float* x      = (const float*)d_in[0];   // [2,2048,1024]
    const float* W_attn = (const float*)d_in[1];   // [1024,3072]
    const float* b_attn = (const float*)d_in[2];   // [3072]
    const float* W_proj = (const float*)d_in[3];   // [1024,1024]
    const float* b_proj = (const float*)d_in[4];   // [1024]
    float* out = (float*)d_out;                    // [2,2048,1024] fp32

    unsigned short* qkv = (unsigned short*)d_ws;             // bf16 [4096,3072] (V third unused)
    unsigned short* y   = qkv + (size_t)4096 * 3072;         // bf16 [4096,1024]
    unsigned short* xb  = y   + (size_t)4096 * 1024;         // bf16 [4096,1024]
    unsigned short* WtA = xb  + (size_t)4096 * 1024;         // bf16 [3072,1024]
    unsigned short* WtP = WtA + (size_t)3072 * 1024;         // bf16 [1024,1024]
    unsigned short* vT  = WtP + (size_t)1024 * 1024;         // bf16 [2048,2048]

    // 0) merged prepass: x->bf16, both weight transposes (one launch)
    prepass<<<dim3(6144), 256, 0, stream>>>(x, xb, W_attn, WtA, W_proj, WtP);

    // 1) qkv = bf16(x @ W_attn + b_attn); Q cols pre-scaled by 0.125*log2e;
    //    V cols (>=2048) transposed to vT.  BK=32 (4 blocks/CU-capable LDS)
    gemm_bt<128, 128, 32, true><<<dim3(3072 / 128, 4096 / 128), 256, 0, stream>>>(
        xb, WtA, b_attn, qkv, 4096, 3072, 1024, 2048, vT, 1024);

    // 2) flash attention -> y bf16 [4096,1024]  (v6b, default dispatch order)
    attn_mfma<<<dim3(BSZ * HNUM, TSEQ / 64), 256, 0, stream>>>(qkv, vT, y);

    // 3) out = y @ W_proj + b_proj (fp32)  M=4096 N=1024 K=1024.
    //    BK=64: 16 K-steps (was 32), 16 MFMA/wave/step, XOR-swizzled LDS;
    //    48 KB LDS -> 3 blocks/CU capable, grid 8x64 = 512 (2/CU)
    gemm_bt<64, 128, 64, false><<<dim3(1024 / 128, 4096 / 64), 256, 0, stream>>>(
        y, WtP, b_proj, out, 4096, 1024, 1024, -1, nullptr, 0);
}

// Round 11
// 174.564 us; speedup vs baseline: 1.1869x; 1.0158x over previous
//
#include <hip/hip_runtime.h>
#include <math.h>

#define BSZ 2
#define TSEQ 2048
#define CDIM 1024
#define HNUM 16

typedef __attribute__((ext_vector_type(8))) short bhalf8;
typedef __attribute__((ext_vector_type(4))) short bhalf4;
typedef __attribute__((ext_vector_type(4))) float floatx4;

__device__ __forceinline__ unsigned short f2bf(float f) {
    union { float f; unsigned u; } v;
    v.f = f;
    unsigned r = v.u + 0x7FFFu + ((v.u >> 16) & 1u);
    return (unsigned short)(r >> 16);
}

__device__ __forceinline__ floatx4 fx4_zero() { floatx4 z = {0.f,0.f,0.f,0.f}; return z; }

// async global->LDS, 16 B per lane. lds dest = (wave-uniform base) + lane*16.
typedef __attribute__((address_space(3))) unsigned int lds_u32;
typedef const __attribute__((address_space(1))) unsigned int g_u32;
__device__ __forceinline__ void async_copy16(const void* g, void* l) {
    __builtin_amdgcn_global_load_lds((g_u32*)g, (lds_u32*)l, 16, 0, 0);
}

// ---------------------------------------------------------------------------
// Merged prepass (one launch):
//  blocks [0,2048):    x fp32 -> xb bf16 (8 elems/thread)
//  blocks [2048,5120): W_attn [1024,3072] -> WtA [3072,1024] bf16 transpose
//  blocks [5120,6144): W_proj [1024,1024] -> WtP [1024,1024] bf16 transpose
// ---------------------------------------------------------------------------
__device__ __forceinline__ void trans_tile(
    const float* __restrict__ W, unsigned short* __restrict__ Wt,
    int K, int N, int n0, int k0, int tid, float (*t)[33])
{
    const int tx = tid & 31, ty = tid >> 5;
#pragma unroll
    for (int i = 0; i < 4; ++i)
        t[ty + i * 8][tx] = W[(size_t)(k0 + ty + i * 8) * N + n0 + tx];
    __syncthreads();
#pragma unroll
    for (int i = 0; i < 4; ++i)
        Wt[(size_t)(n0 + ty + i * 8) * K + k0 + tx] = f2bf(t[tx][ty + i * 8]);
}

__global__ __launch_bounds__(256) void prepass(
    const float* __restrict__ x, unsigned short* __restrict__ xb,
    const float* __restrict__ Wa, unsigned short* __restrict__ WtA,
    const float* __restrict__ Wp, unsigned short* __restrict__ WtP)
{
    __shared__ float t[32][33];
    const int bid = blockIdx.x;
    const int tid = threadIdx.x;
    if (bid < 2048) {
        size_t i = ((size_t)bid * 256 + tid) * 8;
        float4 a = *(const float4*)(x + i);
        float4 b = *(const float4*)(x + i + 4);
        uint4 o;
        o.x = (unsigned)f2bf(a.x) | ((unsigned)f2bf(a.y) << 16);
        o.y = (unsigned)f2bf(a.z) | ((unsigned)f2bf(a.w) << 16);
        o.z = (unsigned)f2bf(b.x) | ((unsigned)f2bf(b.y) << 16);
        o.w = (unsigned)f2bf(b.z) | ((unsigned)f2bf(b.w) << 16);
        *(uint4*)(xb + i) = o;
    } else if (bid < 5120) {
        int tl = bid - 2048;                       // 96 n-tiles x 32 k-tiles
        trans_tile(Wa, WtA, 1024, 3072, (tl % 96) * 32, (tl / 96) * 32, tid, t);
    } else {
        int tl = bid - 5120;                       // 32 x 32
        trans_tile(Wp, WtP, 1024, 1024, (tl % 32) * 32, (tl / 32) * 32, tid, t);
    }
}

// ---------------------------------------------------------------------------
// bf16 MFMA GEMM (B^T input) + bias, single-barrier double-buffered K-loop.
// C[M,N] = A[M,K] @ Bt[N,K]^T + bias[N].  Block tile BM x BN, K-step BK,
// 256 threads (4 waves). Wave covers (BM/2)x(BN/2); acc = MTxNT of 16x16.
// T1 XCD remap (uniform-work GEMM only; REFUTED for causal attn, r8):
// swz = (L%8)*(nwg/8) + L/8, bn-fastest chunk per XCD. nwg%8==0 holds.
// LDS swizzles (T2, both-sides: pre-swizzled GLOBAL source + swizzled read,
// LDS dest linear for global_load_lds):
//  BK=32 (row=64B): slot c = (q + (r>>1)) & 3; read sw8=((quad+(col16>>1))&3)*8
//  BK=64 (row=128B = exact bank wrap, would be 8-way conflicted linear):
//    slot c = q ^ (r&7); read chunk (kk*4+quad) ^ (col16&7) -> each 8-lane
//    phase covers all 32 banks once (attn-K-proven pattern).
// BK=64 halves the barrier count for short-K GEMMs (gemm3, r10: small win).
// gemm1 stays BK=32 (BK=64 would cut occupancy per LDS; m132 lesson).
// Blocks whose colbase >= v_start write TRANSPOSED to vt via ushort4.
// Columns < q_end get scaled by 0.125*log2(e) in fp32 before bf16 round.
// ---------------------------------------------------------------------------
template<int BM, int BN, int BK, bool OUT_BF16>
__global__ __launch_bounds__(256) void gemm_bt(
    const unsigned short* __restrict__ A, const unsigned short* __restrict__ Bt,
    const float* __restrict__ bias, void* __restrict__ Cp,
    int M, int N, int K, int v_start, unsigned short* __restrict__ vt, int q_end)
{
    constexpr int ALINES = (BM * BK) / 2048;   // 256 lanes x 8 shorts per line
    constexpr int BLINES = (BN * BK) / 2048;
    constexpr int MT = BM / 32;
    constexpr int NT = BN / 32;
    constexpr int KK = BK / 32;                 // k-chunks of 32 per step
    constexpr int CPR = BK / 8;                 // 16B-chunks per row
    __shared__ unsigned short As[2][BM * BK];
    __shared__ unsigned short Bs[2][BN * BK];

    const int tid   = threadIdx.x;
    // XCD-aware block remap (bijective: nwg % 8 == 0 for all launches)
    const int nx  = (int)gridDim.x;
    const int lin = (int)(blockIdx.y * gridDim.x + blockIdx.x);
    const int cpx = (int)(gridDim.x * gridDim.y) >> 3;
    const int swz = (lin & 7) * cpx + (lin >> 3);
    const int bn  = swz % nx;
    const int bm  = swz / nx;

    const int wave  = tid >> 6;
    const int col16 = tid & 15;
    const int quad  = (tid & 63) >> 4;
    const int wm    = (wave >> 1) * (BM / 2);
    const int wn    = (wave & 1) * (BN / 2);

    floatx4 acc[MT][NT];
#pragma unroll
    for (int i = 0; i < MT; ++i)
#pragma unroll
        for (int j = 0; j < NT; ++j) acc[i][j] = fx4_zero();

    // staging: lane covers row gr, global k-chunk pre-swizzled per BK scheme
    const int gr = tid / CPR;
    const int cq = tid % CPR;
    const int gk = (BK == 32)
        ? (((cq + 4 - ((gr >> 1) & 3)) & 3) * 8)
        : ((cq ^ (gr & 7)) * 8);
    const unsigned short* Ab = A  + (size_t)(bm * BM + gr) * K + gk;
    const unsigned short* Bb = Bt + (size_t)(bn * BN + gr) * K + gk;
    constexpr int RPL = 2048 / BK;              // rows per staged line

#define STAGE(k0, bf) { \
    char* AsB = (char*)As[bf] + wave * 1024; \
    char* BsB = (char*)Bs[bf] + wave * 1024; \
    _Pragma("unroll") \
    for (int l = 0; l < ALINES; ++l) \
        async_copy16(Ab + (size_t)l * RPL * K + (k0), AsB + l * 4096); \
    _Pragma("unroll") \
    for (int l = 0; l < BLINES; ++l) \
        async_copy16(Bb + (size_t)l * RPL * K + (k0), BsB + l * 4096); }

#define COMPUTE(bf) { \
    _Pragma("unroll") \
    for (int kk = 0; kk < KK; ++kk) { \
        const int sw8 = (BK == 32) \
            ? (((quad + (col16 >> 1)) & 3) * 8) \
            : ((((kk << 2) + quad) ^ (col16 & 7)) * 8); \
        bhalf8 a[MT], b[NT]; \
        _Pragma("unroll") \
        for (int i = 0; i < MT; ++i) \
            a[i] = *(const bhalf8*)&As[bf][(wm + i * 16 + col16) * BK + sw8]; \
        _Pragma("unroll") \
        for (int j = 0; j < NT; ++j) \
            b[j] = *(const bhalf8*)&Bs[bf][(wn + j * 16 + col16) * BK + sw8]; \
        _Pragma("unroll") \
        for (int i = 0; i < MT; ++i) \
            _Pragma("unroll") \
            for (int j = 0; j < NT; ++j) \
                acc[i][j] = __builtin_amdgcn_mfma_f32_16x16x32_bf16(a[i], b[j], acc[i][j], 0, 0, 0); \
    } }

    STAGE(0, 0);
    __syncthreads();
    int buf = 0;
    for (int k0 = 0; k0 < K - BK; k0 += BK) {
        STAGE(k0 + BK, buf ^ 1);
        COMPUTE(buf);
        __syncthreads();
        buf ^= 1;
    }
    COMPUTE(buf);
#undef STAGE
#undef COMPUTE

    const int colbase = bn * BN + wn;
    const bool vpath = (v_start >= 0) && (colbase >= v_start);  // wave-uniform
    const float csc = (colbase < q_end) ? 0.18033688f : 1.0f;   // wave-uniform
#pragma unroll
    for (int j = 0; j < NT; ++j) {
        int col = colbase + j * 16 + col16;
        float bv = bias[col];
#pragma unroll
        for (int i = 0; i < MT; ++i) {
            if (vpath) {
                int row0 = bm * BM + wm + i * 16 + quad * 4;
                ushort4 o;
                o.x = f2bf((acc[i][j][0] + bv) * csc);
                o.y = f2bf((acc[i][j][1] + bv) * csc);
                o.z = f2bf((acc[i][j][2] + bv) * csc);
                o.w = f2bf((acc[i][j][3] + bv) * csc);
                size_t vrow = (size_t)((row0 >> 11) * 1024 + (col - v_start));
                *(ushort4*)(vt + vrow * 2048 + (row0 & 2047)) = o;
            } else {
#pragma unroll
                for (int r = 0; r < 4; ++r) {
                    int row = bm * BM + wm + i * 16 + quad * 4 + r;
                    float v = (acc[i][j][r] + bv) * csc;
                    if (OUT_BF16)
                        ((unsigned short*)Cp)[(size_t)row * N + col] = f2bf(v);
                    else
                        ((float*)Cp)[(size_t)row * N + col] = v;
                }
            }
        }
    }
}

// ---------------------------------------------------------------------------
// MFMA flash attention v6d: v6b datapath (r2/r5/r9-proven) + balanced qb
// permutation.  All 1024 blocks are co-resident (4/CU, LDS-capped), and any
// round-robin dispatch gives a CU blocks with blockIdx.y in {y0,y0+8,y0+16,
// y0+24}.  Old qb=31-y made per-CU tile count 80-4*y0 (80 vs 66 avg ->
// makespan bound by y0=0 CUs).  New bijection qb = {31-r, r, 23-r, 8+r}[y>>3]
// (r=y&7) gives constant per-CU qb-sum 62 -> 66 tiles on EVERY CU.
// Work content/math identical; q-block order is irrelevant.
// REFUTED levers (do not re-apply): split-acc+setprio (r4, +4 us);
// QBLK=128/512thr (r6/r7, +6..11 us); XCD head-chunk remap (r8, +30 us).
// K image:  row*128B + (chunk ^ (row&7))*16B   (async-staged; b128 reads
//   conflict-free). V image: Vt[d*76 + t]; PV b64 read phase bank start
//   = 6*col16 -> conflict-free.
// ---------------------------------------------------------------------------
template<bool DIAG>
__device__ __forceinline__ void attn_tile(
    const unsigned short* __restrict__ Ks, const unsigned short* __restrict__ Vt,
    const bhalf8* qf, floatx4* oT, floatx4& accl,
    int col16, int quad, int qloc)
{
    const int sx = col16 & 7;
    const floatx4 minusC = {-17.31234049f, -17.31234049f, -17.31234049f, -17.31234049f};
    const bhalf4 ones = {0x3F80, 0x3F80, 0x3F80, 0x3F80};   // bf16 1.0 x4

    floatx4 s[4];
#pragma unroll
    for (int n = 0; n < 4; ++n) {
        const int row = 16 * n + col16;
        bhalf8 k0 = *(const bhalf8*)&Ks[row * 64 + ((quad ^ sx) * 8)];
        bhalf8 k1 = *(const bhalf8*)&Ks[row * 64 + (((4 + quad) ^ sx) * 8)];
        floatx4 t = __builtin_amdgcn_mfma_f32_16x16x32_bf16(k0, qf[0], minusC, 0, 0, 0);
        s[n] = __builtin_amdgcn_mfma_f32_16x16x32_bf16(k1, qf[1], t, 0, 0, 0);
    }

    bhalf4 pb[4];
#pragma unroll
    for (int n = 0; n < 4; ++n) {
        unsigned a[4];
#pragma unroll
        for (int r = 0; r < 4; ++r) {
            float p = exp2f(s[n][r]);
            if (DIAG) {
                if (16 * n + quad * 4 + r > qloc) p = 0.f;
            }
            a[r] = __float_as_uint(p) + 0x8000u;   // bias-round to bf16
        }
        union { unsigned u[2]; bhalf4 b; } uu;
        uu.u[0] = (a[0] >> 16) | (a[1] & 0xffff0000u);
        uu.u[1] = (a[2] >> 16) | (a[3] & 0xffff0000u);
        pb[n] = uu.b;
        // l-partial on the MFMA pipe: C[*][q] += sum_k P^T[k][q]
        accl = __builtin_amdgcn_mfma_f32_16x16x16bf16_1k(ones, pb[n], accl, 0, 0, 0);
    }

#pragma unroll
    for (int n = 0; n < 4; ++n) {
#pragma unroll
        for (int dt = 0; dt < 4; ++dt) {
            const int d = 16 * dt + col16;
            const bhalf4 av = *(const bhalf4*)&Vt[d * 76 + 16 * n + quad * 4];
            oT[dt] = __builtin_amdgcn_mfma_f32_16x16x16bf16_1k(av, pb[n], oT[dt], 0, 0, 0);
        }
    }
}

__global__ __launch_bounds__(256) void attn_mfma(
    const unsigned short* __restrict__ qkv,
    const unsigned short* __restrict__ vT,
    unsigned short* __restrict__ yout)
{
    __shared__ unsigned short Kbuf[2][64 * 64];
    __shared__ unsigned short Vbuf[2][64 * 76];

    const int tid   = threadIdx.x;
    const int wave  = tid >> 6;
    const int col16 = tid & 15;
    const int quad  = (tid & 63) >> 4;

    // balanced qb permutation (constant per-CU load; see header comment)
    const int y = (int)blockIdx.y;
    const int g = y >> 3, r = y & 7;
    const int qb = (g == 0) ? 31 - r : (g == 1) ? r : (g == 2) ? 23 - r : 8 + r;

    const int bh    = blockIdx.x;
    const int b     = bh >> 4;
    const int h     = bh & 15;

    const unsigned short* base  = qkv + (size_t)b * TSEQ * 3072 + h * 64;
    const unsigned short* kbase = base + CDIM;
    const unsigned short* vtb   = vT + (size_t)(b * 1024 + h * 64) * 2048;

    // Q fragments (B-layout for S^T): lane holds Q[q=wave*16+col16][d=quad*8+j]
    bhalf8 qf[2];
    {
        const unsigned short* qrow =
            base + (size_t)(qb * 64 + wave * 16 + col16) * 3072 + quad * 8;
        qf[0] = *(const bhalf8*)qrow;
        qf[1] = *(const bhalf8*)(qrow + 32);
    }

    // K staging map: lane covers K row (tid>>3)(+32), chunk (tid&7)^(row&7)
    const int krow = tid >> 3;
    const int kchk = (tid & 7) ^ (krow & 7);
    const unsigned short* ksrc0 = kbase + (size_t)krow * 3072 + kchk * 8;
    const unsigned short* ksrc1 = kbase + (size_t)(krow + 32) * 3072 + kchk * 8;

    // V staging map: lane covers vT row d=(tid>>3)(+32), t chunk (tid&7)*8
    const int vd  = tid >> 3;
    const int vt0 = (tid & 7) * 8;
    const unsigned short* vsrc0 = vtb + (size_t)vd * 2048 + vt0;
    const unsigned short* vsrc1 = vtb + (size_t)(vd + 32) * 2048 + vt0;

#define KSTAGE(kb, bf) { \
    char* Kd = (char*)Kbuf[bf] + wave * 1024; \
    async_copy16(ksrc0 + (size_t)(kb) * 64 * 3072, Kd); \
    async_copy16(ksrc1 + (size_t)(kb) * 64 * 3072, Kd + 4096); }

    floatx4 oT[4];
#pragma unroll
    for (int dt = 0; dt < 4; ++dt) oT[dt] = fx4_zero();
    floatx4 accl = fx4_zero();
    const int qloc = wave * 16 + col16;

    {   // prologue: stage tile 0 into buf 0
        uint4 nv0 = *(const uint4*)vsrc0;
        uint4 nv1 = *(const uint4*)vsrc1;
        KSTAGE(0, 0);
        *(uint4*)&Vbuf[0][vd * 76 + vt0]        = nv0;
        *(uint4*)&Vbuf[0][(vd + 32) * 76 + vt0] = nv1;
    }
    __syncthreads();
    int buf = 0;
    for (int kb = 0; kb < qb; ++kb) {
        uint4 nv0 = *(const uint4*)(vsrc0 + (size_t)(kb + 1) * 64);
        uint4 nv1 = *(const uint4*)(vsrc1 + (size_t)(kb + 1) * 64);
        KSTAGE(kb + 1, buf ^ 1);
        attn_tile<false>(Kbuf[buf], Vbuf[buf], qf, oT, accl, col16, quad, qloc);
        *(uint4*)&Vbuf[buf ^ 1][vd * 76 + vt0]        = nv0;
        *(uint4*)&Vbuf[buf ^ 1][(vd + 32) * 76 + vt0] = nv1;
        __syncthreads();
        buf ^= 1;
    }
    attn_tile<true>(Kbuf[buf], Vbuf[buf], qf, oT, accl, col16, quad, qloc);
#undef KSTAGE

    // epilogue: every lane already holds the full l for its q; O^T/l, store
    const float inv = 1.0f / accl[0];
    const size_t row = (size_t)b * TSEQ + (size_t)qb * 64 + wave * 16 + col16;
#pragma unroll
    for (int dt = 0; dt < 4; ++dt) {
        ushort4 o;
        o.x = f2bf(oT[dt][0] * inv);
        o.y = f2bf(oT[dt][1] * inv);
        o.z = f2bf(oT[dt][2] * inv);
        o.w = f2bf(oT[dt][3] * inv);
        *(ushort4*)(yout + row * CDIM + h * 64 + 16 * dt + quad * 4) = o;
    }
}

// ---------------------------------------------------------------------------
extern "C" void kernel_launch(void* const* d_in, const int* in_sizes, int n_in,
                              void* d_out, int out_size, void* d_ws, size_t ws_size,
                              hipStream_t stream)
{
    const float* x      = (const float*)d_in[0];   // [2,2048,1024]
    const float* W_attn = (const float*)d_in[1];   // [1024,3072]
    const float* b_attn = (const float*)d_in[2];   // [3072]
    const float* W_proj = (const float*)d_in[3];   // [1024,1024]
    const float* b_proj = (const float*)d_in[4];   // [1024]
    float* out = (float*)d_out;                    // [2,2048,1024] fp32

    unsigned short* qkv = (unsigned short*)d_ws;             // bf16 [4096,3072] (V third unused)
    unsigned short* y   = qkv + (size_t)4096 * 3072;         // bf16 [4096,1024]
    unsigned short* xb  = y   + (size_t)4096 * 1024;         // bf16 [4096,1024]
    unsigned short* WtA = xb  + (size_t)4096 * 1024;         // bf16 [3072,1024]
    unsigned short* WtP = WtA + (size_t)3072 * 1024;         // bf16 [1024,1024]
    unsigned short* vT  = WtP + (size_t)1024 * 1024;         // bf16 [2048,2048]

    // 0) merged prepass: x->bf16, both weight transposes (one launch)
    prepass<<<dim3(6144), 256, 0, stream>>>(x, xb, W_attn, WtA, W_proj, WtP);

    // 1) qkv = bf16(x @ W_attn + b_attn); Q cols pre-scaled by 0.125*log2e;
    //    V cols (>=2048) transposed to vT.  BK=32 (4 blocks/CU-capable LDS)
    gemm_bt<128, 128, 32, true><<<dim3(3072 / 128, 4096 / 128), 256, 0, stream>>>(
        xb, WtA, b_attn, qkv, 4096, 3072, 1024, 2048, vT, 1024);

    // 2) flash attention -> y bf16 [4096,1024]  (v6d: balanced qb permutation)
    attn_mfma<<<dim3(BSZ * HNUM, TSEQ / 64), 256, 0, stream>>>(qkv, vT, y);

    // 3) out = y @ W_proj + b_proj (fp32)  M=4096 N=1024 K=1024.
    //    BK=64: 16 K-steps, 16 MFMA/wave/step, XOR-swizzled LDS
    gemm_bt<64, 128, 64, false><<<dim3(1024 / 128, 4096 / 64), 256, 0, stream>>>(
        y, WtP, b_proj, out, 4096, 1024, 1024, -1, nullptr, 0);
}